// Round 27
// baseline (13.278 us; speedup 1.0000x reference)
//
#include <hip/hip_runtime.h>
#include <hip/hip_bf16.h>

#define NE    32
#define DIN   256
#define DOUT  256
#define TN    32     // output cols per block (R27 test: 32 @ 4 blocks/CU)
#define SPL   4      // token-split factor

typedef __attribute__((ext_vector_type(8))) short short8v;   // 8 bf16 = 4 VGPR
typedef __attribute__((ext_vector_type(4))) float float4v;   // MFMA accumulator

// fp32x2 -> packed bf16x2 via native intrinsic (R26-proven, RNE)
__device__ __forceinline__ unsigned pk2(float lo, float hi) {
    __hip_bfloat16 bl = __float2bfloat16(lo);
    __hip_bfloat16 bh = __float2bfloat16(hi);
    const unsigned short ul = *reinterpret_cast<const unsigned short*>(&bl);
    const unsigned short uh = *reinterpret_cast<const unsigned short*>(&bh);
    return (unsigned)ul | ((unsigned)uh << 16);
}

// v12: the last untested geometry cell -- TN=32 at 4 blocks/CU with ALL the
// post-R18 prologue improvements (W-prefetch-before-collect q[4][8] = 32 VGPR
// fits the (256,4) cap; single-barrier collect; native cvt; nt stores).
// Mechanism: the remaining cost is exposed cold-miss latency; 4 resident
// blocks/CU double the overlap. Cost: 2x x-rereads + 2x collects (R16->R18
// priced at ~1.4us under the OLD serial prologue; new prologue overlaps most).
// Pre-commit: if >= 12.05us, R26 champion stands and session is at plateau.
__global__ __launch_bounds__(256, 4) void moe_mfma_kernel(
    const float* __restrict__ x, const int* __restrict__ idx,
    const float* __restrict__ w, const float* __restrict__ bias,
    float* __restrict__ out)
{
    __shared__ unsigned short wls[16 * 64 * 8];   // 16 KB, fragment-major [kk*2+h][lane][i]
    __shared__ unsigned short toklist[4096];      //  8 KB
    __shared__ int wcnt[4][4];                    // [round][wave]

    const int tid   = threadIdx.x;
    const int e     = blockIdx.x & 31;          // expert; XCD = bx%8 = e%8
    const int cb    = (blockIdx.x >> 5) & 7;    // 32-col slice
    const int s     = blockIdx.x >> 8;          // token split 0..3
    const int obase = cb * TN;
    const int lane  = tid & 63;
    const int wid   = tid >> 6;
    const unsigned long long lt = (1ull << lane) - 1ull;

    // ---- issue idx loads ----
    int4 v0 = *reinterpret_cast<const int4*>(idx + 0 * 1024 + tid * 4);
    int4 v1 = *reinterpret_cast<const int4*>(idx + 1 * 1024 + tid * 4);
    int4 v2 = *reinterpret_cast<const int4*>(idx + 2 * 1024 + tid * 4);
    int4 v3 = *reinterpret_cast<const int4*>(idx + 3 * 1024 + tid * 4);

    // ---- issue ALL W loads now; they complete under the collect (T14) ----
    // frag(kk,h,l) element i = W[kk*32 + (l>>4)*8 + i][obase + h*16 + (l&15)]
    float q[4][8];
#pragma unroll
    for (int f = 0; f < 4; ++f) {
        const int fid   = f * 256 + tid;
        const int k2h   = fid >> 6;      // kk*2+h, 0..15
        const int lp    = fid & 63;
        const int kbase = (k2h >> 1) * 32 + (lp >> 4) * 8;
        const int c     = obase + (k2h & 1) * 16 + (lp & 15);
        const float* wp = w + (size_t)e * DIN * DOUT + (size_t)kbase * DOUT + c;
#pragma unroll
        for (int i = 0; i < 8; ++i) q[f][i] = wp[(size_t)i * DOUT];
    }
    __builtin_amdgcn_sched_barrier(0);   // pin: all loads issued before ballot work

    // ---- collect phase A: per-round per-wave counts (no barriers) ----
#define COUNT(vv, r)                                                                   \
    {                                                                                  \
        const int p0 = __popcll(__ballot((vv).x == e));                                \
        const int p1 = __popcll(__ballot((vv).y == e));                                \
        const int p2 = __popcll(__ballot((vv).z == e));                                \
        const int p3 = __popcll(__ballot((vv).w == e));                                \
        if (lane == 0) wcnt[r][wid] = p0 + p1 + p2 + p3;                               \
    }
    COUNT(v0, 0) COUNT(v1, 1) COUNT(v2, 2) COUNT(v3, 3)
#undef COUNT
    __syncthreads();   // ONE barrier; vmcnt drain completes idx + all W loads here

    // ---- collect phase B: totals, prefixes, toklist writes ----
    int ce = 0;
#pragma unroll
    for (int r = 0; r < 4; ++r) ce += wcnt[r][0] + wcnt[r][1] + wcnt[r][2] + wcnt[r][3];
    if (ce <= s * 64) return;   // block-uniform: this split has no token groups

    int running = 0;
#define SCATTER(vv, r)                                                                 \
    {                                                                                  \
        const int tb = (r) * 1024 + tid * 4;                                           \
        const unsigned long long m0 = __ballot((vv).x == e);                           \
        const unsigned long long m1 = __ballot((vv).y == e);                           \
        const unsigned long long m2 = __ballot((vv).z == e);                           \
        const unsigned long long m3 = __ballot((vv).w == e);                           \
        int wb = running;                                                              \
        if (wid > 0) wb += wcnt[r][0];                                                 \
        if (wid > 1) wb += wcnt[r][1];                                                 \
        if (wid > 2) wb += wcnt[r][2];                                                 \
        const int b0 = wb, b1 = b0 + __popcll(m0), b2 = b1 + __popcll(m1), b3 = b2 + __popcll(m2); \
        if ((vv).x == e) toklist[b0 + __popcll(m0 & lt)] = (unsigned short)(tb + 0);   \
        if ((vv).y == e) toklist[b1 + __popcll(m1 & lt)] = (unsigned short)(tb + 1);   \
        if ((vv).z == e) toklist[b2 + __popcll(m2 & lt)] = (unsigned short)(tb + 2);   \
        if ((vv).w == e) toklist[b3 + __popcll(m3 & lt)] = (unsigned short)(tb + 3);   \
        running += wcnt[r][0] + wcnt[r][1] + wcnt[r][2] + wcnt[r][3];                  \
    }
    SCATTER(v0, 0) SCATTER(v1, 1) SCATTER(v2, 2) SCATTER(v3, 3)
#undef SCATTER

    // ---- W cvt + LDS store (q already resident) ----
#pragma unroll
    for (int f = 0; f < 4; ++f) {
        const int fid = f * 256 + tid;
        const int k2h = fid >> 6;
        const int lp  = fid & 63;
        uint4 pk;
        pk.x = pk2(q[f][0], q[f][1]);
        pk.y = pk2(q[f][2], q[f][3]);
        pk.z = pk2(q[f][4], q[f][5]);
        pk.w = pk2(q[f][6], q[f][7]);
        *reinterpret_cast<uint4*>(&wls[(size_t)(k2h * 64 + lp) * 8]) = pk;
    }
    __syncthreads();   // toklist + wls ready

    // fragment lane roles (16x16x32 bf16, R10-verified):
    //   A: row = lane&15 (token slot), k = (lane>>4)*8 + i
    //   B: col = lane&15 (+16h), k = (lane>>4)*8 + i  (= frag(kk,h,lane))
    //   C/D: col = lane&15, row = (lane>>4)*4 + reg
    const int a15 = lane & 15;
    const int kg  = lane >> 4;
    const float bv0 = bias[(size_t)e * DOUT + obase + a15];
    const float bv1 = bias[(size_t)e * DOUT + obase + 16 + a15];

#pragma unroll 1
    for (int tb0 = (s * 4 + wid) * 16; tb0 < ce; tb0 += SPL * 64) {
        const int tok = toklist[min(tb0 + a15, ce - 1)];
        const float* xr = x + (size_t)tok * DIN + kg * 8;

        float4 L[16];
#pragma unroll
        for (int kk = 0; kk < 8; ++kk) {
            L[2 * kk]     = *reinterpret_cast<const float4*>(xr + kk * 32);
            L[2 * kk + 1] = *reinterpret_cast<const float4*>(xr + kk * 32 + 4);
        }
        __builtin_amdgcn_sched_barrier(0);   // all 16 loads issue before any use

        float4v acc0 = {0.f, 0.f, 0.f, 0.f};
        float4v acc1 = {0.f, 0.f, 0.f, 0.f};
#pragma unroll
        for (int kk = 0; kk < 8; ++kk) {
            uint4 ua;
            ua.x = pk2(L[2 * kk].x,     L[2 * kk].y);
            ua.y = pk2(L[2 * kk].z,     L[2 * kk].w);
            ua.z = pk2(L[2 * kk + 1].x, L[2 * kk + 1].y);
            ua.w = pk2(L[2 * kk + 1].z, L[2 * kk + 1].w);
            const short8v a  = __builtin_bit_cast(short8v, ua);
            const short8v b0 = *reinterpret_cast<const short8v*>(&wls[((kk * 2 + 0) * 64 + lane) * 8]);
            const short8v b1 = *reinterpret_cast<const short8v*>(&wls[((kk * 2 + 1) * 64 + lane) * 8]);
            acc0 = __builtin_amdgcn_mfma_f32_16x16x32_bf16(a, b0, acc0, 0, 0, 0);
            acc1 = __builtin_amdgcn_mfma_f32_16x16x32_bf16(a, b1, acc1, 0, 0, 0);
        }

#pragma unroll
        for (int r = 0; r < 4; ++r) {
            const int sl = tb0 + kg * 4 + r;
            if (sl < ce) {
                const int row = toklist[sl];
                float* op = out + (size_t)row * DOUT + obase;
                __builtin_nontemporal_store(acc0[r] + bv0, op + a15);
                __builtin_nontemporal_store(acc1[r] + bv1, op + 16 + a15);
            }
        }
    }
}

extern "C" void kernel_launch(void* const* d_in, const int* in_sizes, int n_in,
                              void* d_out, int out_size, void* d_ws, size_t ws_size,
                              hipStream_t stream) {
    const float* x      = (const float*)d_in[0];
    const int*   index  = (const int*)d_in[1];
    const float* weight = (const float*)d_in[2];
    const float* bias   = (const float*)d_in[3];
    float* out = (float*)d_out;

    // 4 splits x 8 col-slices x 32 experts = 1024 blocks = 4/CU; bx%8 = e%8 (XCD)
    moe_mfma_kernel<<<SPL * 8 * NE, 256, 0, stream>>>(x, index, weight, bias, out);
}

// Round 28
// 11.894 us; speedup vs baseline: 1.1163x; 1.1163x over previous
//
#include <hip/hip_runtime.h>
#include <hip/hip_bf16.h>

#define NE    32
#define DIN   256
#define DOUT  256
#define TN    64     // output cols per block
#define SPL   4      // token-split factor

typedef __attribute__((ext_vector_type(8))) short short8v;   // 8 bf16 = 4 VGPR
typedef __attribute__((ext_vector_type(4))) float float4v;   // MFMA accumulator

// fp32x2 -> packed bf16x2 via native intrinsic (RNE; R26-proven)
__device__ __forceinline__ unsigned pk2(float lo, float hi) {
    __hip_bfloat16 bl = __float2bfloat16(lo);
    __hip_bfloat16 bh = __float2bfloat16(hi);
    const unsigned short ul = *reinterpret_cast<const unsigned short*>(&bl);
    const unsigned short uh = *reinterpret_cast<const unsigned short*>(&bh);
    return (unsigned)ul | ((unsigned)uh << 16);
}

// FINAL = R26 champion (12.05us, PASSED) restored verbatim. Session geometry x
// prologue matrix fully explored; every neighbor of this cell regresses:
//   R17 split-kernels 17.7 | R21 512-thr 13.5 | R22 wave-windows 13.5
//   R23 atomic-collect FAIL | R27 TN=32@4blk 13.3
// Structure: fused routing (ballot prefix, single mid-chain barrier),
// W-prefetch-before-collect (T14: HBM latency under ballot work),
// fragment-major conflict-free wls, batched 16-load x gather with
// sched_barrier-forced MLP, native bf16 cvt, nontemporal out stores.
// Remaining ~12us = warm chain ~6.9us (R19 REP-measured) + cold first-touch
// + launch/replay overhead -- a latency floor, not a counter-visible roofline.
__global__ __launch_bounds__(256, 2) void moe_mfma_kernel(
    const float* __restrict__ x, const int* __restrict__ idx,
    const float* __restrict__ w, const float* __restrict__ bias,
    float* __restrict__ out)
{
    __shared__ unsigned short wls[32 * 64 * 8];   // 32 KB, fragment-major [kk*4+h][lane][i]
    __shared__ unsigned short toklist[4096];      //  8 KB
    __shared__ int wcnt[4][4];                    // [round][wave]

    const int tid   = threadIdx.x;
    const int e     = blockIdx.x & 31;          // expert; XCD = bx%8 = e%8
    const int cb    = (blockIdx.x >> 5) & 3;    // 64-col slice
    const int s     = blockIdx.x >> 7;          // token split 0..3
    const int obase = cb * TN;
    const int lane  = tid & 63;
    const int wid   = tid >> 6;
    const unsigned long long lt = (1ull << lane) - 1ull;

    // ---- issue idx loads (needed before first barrier) ----
    int4 v0 = *reinterpret_cast<const int4*>(idx + 0 * 1024 + tid * 4);
    int4 v1 = *reinterpret_cast<const int4*>(idx + 1 * 1024 + tid * 4);
    int4 v2 = *reinterpret_cast<const int4*>(idx + 2 * 1024 + tid * 4);
    int4 v3 = *reinterpret_cast<const int4*>(idx + 3 * 1024 + tid * 4);

    // ---- issue ALL W loads now; they complete under the collect (T14) ----
    // frag(kk,h,l) element i = W[kk*32 + (l>>4)*8 + i][obase + h*16 + (l&15)]
    float q[8][8];
#pragma unroll
    for (int f = 0; f < 8; ++f) {
        const int fid   = f * 256 + tid;
        const int k2h   = fid >> 6;      // kk*4+h
        const int lp    = fid & 63;
        const int kbase = (k2h >> 2) * 32 + (lp >> 4) * 8;
        const int c     = obase + (k2h & 3) * 16 + (lp & 15);
        const float* wp = w + (size_t)e * DIN * DOUT + (size_t)kbase * DOUT + c;
#pragma unroll
        for (int i = 0; i < 8; ++i) q[f][i] = wp[(size_t)i * DOUT];
    }
    __builtin_amdgcn_sched_barrier(0);   // pin: all loads issued before ballot work

    // ---- collect phase A: per-round per-wave counts (no barriers) ----
#define COUNT(vv, r)                                                                   \
    {                                                                                  \
        const int p0 = __popcll(__ballot((vv).x == e));                                \
        const int p1 = __popcll(__ballot((vv).y == e));                                \
        const int p2 = __popcll(__ballot((vv).z == e));                                \
        const int p3 = __popcll(__ballot((vv).w == e));                                \
        if (lane == 0) wcnt[r][wid] = p0 + p1 + p2 + p3;                               \
    }
    COUNT(v0, 0) COUNT(v1, 1) COUNT(v2, 2) COUNT(v3, 3)
#undef COUNT
    __syncthreads();   // ONE barrier; vmcnt drain completes idx + all W loads here

    // ---- collect phase B: totals, prefixes, toklist writes (recomputed ballots) ----
    int ce = 0;
#pragma unroll
    for (int r = 0; r < 4; ++r) ce += wcnt[r][0] + wcnt[r][1] + wcnt[r][2] + wcnt[r][3];
    if (ce <= s * 64) return;   // block-uniform: this split has no token groups

    int running = 0;
#define SCATTER(vv, r)                                                                 \
    {                                                                                  \
        const int tb = (r) * 1024 + tid * 4;                                           \
        const unsigned long long m0 = __ballot((vv).x == e);                           \
        const unsigned long long m1 = __ballot((vv).y == e);                           \
        const unsigned long long m2 = __ballot((vv).z == e);                           \
        const unsigned long long m3 = __ballot((vv).w == e);                           \
        int wb = running;                                                              \
        if (wid > 0) wb += wcnt[r][0];                                                 \
        if (wid > 1) wb += wcnt[r][1];                                                 \
        if (wid > 2) wb += wcnt[r][2];                                                 \
        const int b0 = wb, b1 = b0 + __popcll(m0), b2 = b1 + __popcll(m1), b3 = b2 + __popcll(m2); \
        if ((vv).x == e) toklist[b0 + __popcll(m0 & lt)] = (unsigned short)(tb + 0);   \
        if ((vv).y == e) toklist[b1 + __popcll(m1 & lt)] = (unsigned short)(tb + 1);   \
        if ((vv).z == e) toklist[b2 + __popcll(m2 & lt)] = (unsigned short)(tb + 2);   \
        if ((vv).w == e) toklist[b3 + __popcll(m3 & lt)] = (unsigned short)(tb + 3);   \
        running += wcnt[r][0] + wcnt[r][1] + wcnt[r][2] + wcnt[r][3];                  \
    }
    SCATTER(v0, 0) SCATTER(v1, 1) SCATTER(v2, 2) SCATTER(v3, 3)
#undef SCATTER

    // ---- W cvt + LDS store (q already resident) ----
#pragma unroll
    for (int f = 0; f < 8; ++f) {
        const int fid = f * 256 + tid;
        const int k2h = fid >> 6;
        const int lp  = fid & 63;
        uint4 pk;
        pk.x = pk2(q[f][0], q[f][1]);
        pk.y = pk2(q[f][2], q[f][3]);
        pk.z = pk2(q[f][4], q[f][5]);
        pk.w = pk2(q[f][6], q[f][7]);
        *reinterpret_cast<uint4*>(&wls[(size_t)(k2h * 64 + lp) * 8]) = pk;
    }
    __syncthreads();   // toklist + wls ready

    // fragment lane roles (16x16x32 bf16, R10-verified):
    //   A: row = lane&15 (token slot), k = (lane>>4)*8 + i
    //   B: col = lane&15 (+16h), k = (lane>>4)*8 + i  (= frag(kk,h,lane))
    //   C/D: col = lane&15, row = (lane>>4)*4 + reg
    const int a15 = lane & 15;
    const int kg  = lane >> 4;
    const float* bp = bias + (size_t)e * DOUT + obase + a15;
    const float bv0 = bp[0], bv1 = bp[16], bv2 = bp[32], bv3 = bp[48];

#pragma unroll 1
    for (int tb0 = (s * 4 + wid) * 16; tb0 < ce; tb0 += SPL * 64) {
        const int tok = toklist[min(tb0 + a15, ce - 1)];
        const float* xr = x + (size_t)tok * DIN + kg * 8;

        float4 L[16];
#pragma unroll
        for (int kk = 0; kk < 8; ++kk) {
            L[2 * kk]     = *reinterpret_cast<const float4*>(xr + kk * 32);
            L[2 * kk + 1] = *reinterpret_cast<const float4*>(xr + kk * 32 + 4);
        }
        __builtin_amdgcn_sched_barrier(0);   // all 16 loads issue before any use

        float4v acc0 = {0.f, 0.f, 0.f, 0.f};
        float4v acc1 = {0.f, 0.f, 0.f, 0.f};
        float4v acc2 = {0.f, 0.f, 0.f, 0.f};
        float4v acc3 = {0.f, 0.f, 0.f, 0.f};
#pragma unroll
        for (int kk = 0; kk < 8; ++kk) {
            uint4 ua;
            ua.x = pk2(L[2 * kk].x,     L[2 * kk].y);
            ua.y = pk2(L[2 * kk].z,     L[2 * kk].w);
            ua.z = pk2(L[2 * kk + 1].x, L[2 * kk + 1].y);
            ua.w = pk2(L[2 * kk + 1].z, L[2 * kk + 1].w);
            const short8v a  = __builtin_bit_cast(short8v, ua);
            const short8v b0 = *reinterpret_cast<const short8v*>(&wls[((kk * 4 + 0) * 64 + lane) * 8]);
            const short8v b1 = *reinterpret_cast<const short8v*>(&wls[((kk * 4 + 1) * 64 + lane) * 8]);
            const short8v b2 = *reinterpret_cast<const short8v*>(&wls[((kk * 4 + 2) * 64 + lane) * 8]);
            const short8v b3 = *reinterpret_cast<const short8v*>(&wls[((kk * 4 + 3) * 64 + lane) * 8]);
            acc0 = __builtin_amdgcn_mfma_f32_16x16x32_bf16(a, b0, acc0, 0, 0, 0);
            acc1 = __builtin_amdgcn_mfma_f32_16x16x32_bf16(a, b1, acc1, 0, 0, 0);
            acc2 = __builtin_amdgcn_mfma_f32_16x16x32_bf16(a, b2, acc2, 0, 0, 0);
            acc3 = __builtin_amdgcn_mfma_f32_16x16x32_bf16(a, b3, acc3, 0, 0, 0);
        }

#pragma unroll
        for (int r = 0; r < 4; ++r) {
            const int sl = tb0 + kg * 4 + r;
            if (sl < ce) {
                const int row = toklist[sl];
                float* op = out + (size_t)row * DOUT + obase;
                __builtin_nontemporal_store(acc0[r] + bv0, op + a15);
                __builtin_nontemporal_store(acc1[r] + bv1, op + 16 + a15);
                __builtin_nontemporal_store(acc2[r] + bv2, op + 32 + a15);
                __builtin_nontemporal_store(acc3[r] + bv3, op + 48 + a15);
            }
        }
    }
}

extern "C" void kernel_launch(void* const* d_in, const int* in_sizes, int n_in,
                              void* d_out, int out_size, void* d_ws, size_t ws_size,
                              hipStream_t stream) {
    const float* x      = (const float*)d_in[0];
    const int*   index  = (const int*)d_in[1];
    const float* weight = (const float*)d_in[2];
    const float* bias   = (const float*)d_in[3];
    float* out = (float*)d_out;

    // 4 splits x 4 col-slices x 32 experts = 512 blocks = 2/CU; bx%8 = e%8 (XCD)
    moe_mfma_kernel<<<SPL * 4 * NE, 256, 0, stream>>>(x, index, weight, bias, out);
}